// Round 13
// baseline (277.626 us; speedup 1.0000x reference)
//
#include <hip/hip_runtime.h>
#include <hip/hip_fp16.h>

// GNNPolicy forward: 2-layer GCN + actor head + mean-pool critic head.
// N=100K, E=1.6M, H=64, G=64. CSR build: 2-level counting sort with
// block-private reservations; records carry (row,|ea|). xw and h stored fp16
// (f32 accumulation everywhere). Logits fused into layer-2 aggregation.

#define TB 256
#define BSH2 9
#define BW2 512          // nodes per coarse bucket
#define CHUNK 4096       // edges per passA block
#define NB1MAX 256       // max coarse buckets (N <= 131072, row fits 17 bits)

// ---- pass A: LDS histogram + region reservation + dense 8B-record append ----
// recA = ( (colLocal<<17) | row , |ea| )
__global__ __launch_bounds__(256) void passA_k(const int* __restrict__ col,
                                               const int* __restrict__ row,
                                               const float* __restrict__ ea,
                                               int* __restrict__ gCur,
                                               uint2* __restrict__ recA,
                                               int E, int CAPB, int NB1) {
    __shared__ int hist[NB1MAX], base[NB1MAX], cur[NB1MAX];
    int t = threadIdx.x;
    int e0 = blockIdx.x * CHUNK;
    if (t < NB1MAX) { hist[t] = 0; cur[t] = 0; }
    __syncthreads();
    for (int i = t; i < CHUNK; i += 256) {
        int e = e0 + i;
        if (e < E) atomicAdd(&hist[col[e] >> BSH2], 1);
    }
    __syncthreads();
    if (t < NB1) base[t] = atomicAdd(&gCur[t], hist[t]);
    __syncthreads();
    for (int i = t; i < CHUNK; i += 256) {
        int e = e0 + i;
        if (e >= E) continue;
        int c = col[e];
        int b = c >> BSH2;
        int pos = base[b] + atomicAdd(&cur[b], 1);
        if (pos < CAPB)   // statistically impossible overflow; guard anyway
            recA[(size_t)b * CAPB + pos] =
                make_uint2(((unsigned)(c & (BW2 - 1)) << 17) | (unsigned)row[e],
                           __float_as_uint(fabsf(ea[e])));
    }
}

// ---- pass B: per-bucket exact binning -> CSR (row,|ea|) + ptr/cnt + dis ----
__global__ __launch_bounds__(256) void passB_k(const int* __restrict__ gCur,
                                               const uint2* __restrict__ recA,
                                               uint2* __restrict__ rec,
                                               int* __restrict__ ptr,
                                               int* __restrict__ cnt,
                                               float* __restrict__ dis,
                                               int N, int CAPB) {
    __shared__ int hist[BW2], excl[BW2], cur[BW2];
    __shared__ float sumL[BW2];
    __shared__ int part[256];
    int b = blockIdx.x, t = threadIdx.x;
    int nrec = min(gCur[b], CAPB);
    for (int i = t; i < BW2; i += 256) { hist[i] = 0; cur[i] = 0; sumL[i] = 0.f; }
    __syncthreads();
    const uint2* ra = recA + (size_t)b * CAPB;
    for (int i = t; i < nrec; i += 256) {
        uint2 r = ra[i];
        int lc = r.x >> 17;
        atomicAdd(&hist[lc], 1);
        atomicAdd(&sumL[lc], __uint_as_float(r.y));
    }
    __syncthreads();
    // block exclusive scan over 512 counters (2 per thread)
    int s0 = hist[t * 2], s = s0 + hist[t * 2 + 1];
    part[t] = s;
    __syncthreads();
    for (int d = 1; d < 256; d <<= 1) {
        int v = (t >= d) ? part[t - d] : 0;
        __syncthreads();
        part[t] += v;
        __syncthreads();
    }
    int poff = t ? part[t - 1] : 0;
    excl[t * 2] = poff;
    excl[t * 2 + 1] = poff + s0;
    __syncthreads();
    for (int i = t; i < nrec; i += 256) {     // recA bucket is L2-hot (re-read)
        uint2 r = ra[i];
        int lc = r.x >> 17;
        int pos = atomicAdd(&cur[lc], 1);
        rec[(size_t)b * CAPB + excl[lc] + pos] = make_uint2(r.x & 0x1FFFFu, r.y);
    }
    int c0 = b << BSH2;
    for (int i = t; i < BW2; i += 256) {
        int node = c0 + i;
        if (node < N) {
            ptr[node] = b * CAPB + excl[i];
            cnt[node] = hist[i];
            dis[node] = rsqrtf(sumL[i] + 1.0f);
        }
    }
}

// Y[N,64] = X[N,K] @ W[K,64], output fp16. 256 thr = 16 rows x 64 cols.
// T = float (layer 1) or __half (layer 2); LDS/accumulation stay f32.
template <int K, typename T>
__global__ __launch_bounds__(256) void gemm_k(const T* __restrict__ X,
                                              const float* __restrict__ W,
                                              __half* __restrict__ Y, int N) {
    __shared__ float xs[16 * K];
    const int tid = threadIdx.x;
    const int row0 = blockIdx.x * 16;
    float4* xs4 = reinterpret_cast<float4*>(xs);
    if constexpr (sizeof(T) == 4) {
        const float4* X4 = reinterpret_cast<const float4*>((const float*)X + (size_t)row0 * K);
        for (int idx = tid; idx < 16 * K / 4; idx += 256) {
            int r = row0 + (idx * 4) / K;
            xs4[idx] = (r < N) ? X4[idx] : float4{0.f, 0.f, 0.f, 0.f};
        }
    } else {
        const __half2* X2 = reinterpret_cast<const __half2*>((const __half*)X + (size_t)row0 * K);
        for (int idx = tid; idx < 16 * K / 4; idx += 256) {
            int r = row0 + (idx * 4) / K;
            if (r < N) {
                float2 fa = __half22float2(X2[2 * idx]);
                float2 fb = __half22float2(X2[2 * idx + 1]);
                xs4[idx] = float4{fa.x, fa.y, fb.x, fb.y};
            } else xs4[idx] = float4{0.f, 0.f, 0.f, 0.f};
        }
    }
    __syncthreads();
    const int c  = tid & 63;
    const int rg = tid >> 6;
    const float4* xp0 = reinterpret_cast<const float4*>(xs + (rg * 4 + 0) * K);
    const float4* xp1 = reinterpret_cast<const float4*>(xs + (rg * 4 + 1) * K);
    const float4* xp2 = reinterpret_cast<const float4*>(xs + (rg * 4 + 2) * K);
    const float4* xp3 = reinterpret_cast<const float4*>(xs + (rg * 4 + 3) * K);
    float a0 = 0.f, a1 = 0.f, a2 = 0.f, a3 = 0.f;
#pragma unroll 2
    for (int k4 = 0; k4 < K / 4; ++k4) {
        float4 x0 = xp0[k4], x1 = xp1[k4], x2 = xp2[k4], x3 = xp3[k4];
        const float* wp = W + k4 * 4 * 64 + c;
        float w0 = wp[0], w1 = wp[64], w2 = wp[128], w3 = wp[192];
        a0 = fmaf(x0.x, w0, a0); a0 = fmaf(x0.y, w1, a0);
        a0 = fmaf(x0.z, w2, a0); a0 = fmaf(x0.w, w3, a0);
        a1 = fmaf(x1.x, w0, a1); a1 = fmaf(x1.y, w1, a1);
        a1 = fmaf(x1.z, w2, a1); a1 = fmaf(x1.w, w3, a1);
        a2 = fmaf(x2.x, w0, a2); a2 = fmaf(x2.y, w1, a2);
        a2 = fmaf(x2.z, w2, a2); a2 = fmaf(x2.w, w3, a2);
        a3 = fmaf(x3.x, w0, a3); a3 = fmaf(x3.y, w1, a3);
        a3 = fmaf(x3.z, w2, a3); a3 = fmaf(x3.w, w3, a3);
    }
    int r = row0 + rg * 4;
    if (r < N)     Y[(size_t)r * 64 + c]       = __float2half(a0);
    if (r + 1 < N) Y[(size_t)(r + 1) * 64 + c] = __float2half(a1);
    if (r + 2 < N) Y[(size_t)(r + 2) * 64 + c] = __float2half(a2);
    if (r + 3 < N) Y[(size_t)(r + 3) * 64 + c] = __float2half(a3);
}

// CSR gather aggregation fused with self-loop + bias + ReLU (+ actor logits
// for layer 2). Wave per node; 2 edges per step: lanes 0-31 even edges,
// 32-63 odd edges; each lane loads one half2. h written as fp16.
template <bool WITH_LOGITS>
__global__ __launch_bounds__(256) void agg_fin_k(const int* __restrict__ ptr,
                                                 const int* __restrict__ cnt,
                                                 const uint2* __restrict__ rec,
                                                 const float* __restrict__ dis,
                                                 const __half2* __restrict__ xw2,
                                                 const float* __restrict__ bias,
                                                 __half2* __restrict__ hout,
                                                 const float* __restrict__ aw,
                                                 const float* __restrict__ ab,
                                                 float* __restrict__ logits, int N) {
    int n = blockIdx.x * 4 + (threadIdx.x >> 6);
    if (n >= N) return;
    int lane = threadIdx.x & 63;
    int half_id = lane >> 5;          // 0: even edges, 1: odd edges
    int fl = lane & 31;               // feature pair (2fl, 2fl+1)
    int base = ptr[n], num = cnt[n];
    float ax = 0.f, ay = 0.f;
    for (int k0 = 0; k0 < num; k0 += 64) {
        int rem = min(num - k0, 64);
        int r = 0; float w = 0.f;
        if (lane < rem) {
            uint2 rv = rec[(size_t)base + k0 + lane];   // coalesced 512B
            r = (int)rv.x;
            w = __uint_as_float(rv.y) * dis[r];         // 400KB table: L2-hot
        }
        int k = 0;
        for (; k + 15 < rem; k += 16) {
            int i0 = k + half_id;
            int   ra0 = __shfl(r, i0),      ra1 = __shfl(r, i0 + 2);
            int   ra2 = __shfl(r, i0 + 4),  ra3 = __shfl(r, i0 + 6);
            int   ra4 = __shfl(r, i0 + 8),  ra5 = __shfl(r, i0 + 10);
            int   ra6 = __shfl(r, i0 + 12), ra7 = __shfl(r, i0 + 14);
            float wa0 = __shfl(w, i0),      wa1 = __shfl(w, i0 + 2);
            float wa2 = __shfl(w, i0 + 4),  wa3 = __shfl(w, i0 + 6);
            float wa4 = __shfl(w, i0 + 8),  wa5 = __shfl(w, i0 + 10);
            float wa6 = __shfl(w, i0 + 12), wa7 = __shfl(w, i0 + 14);
            __half2 v0 = xw2[(size_t)ra0 * 32 + fl];
            __half2 v1 = xw2[(size_t)ra1 * 32 + fl];
            __half2 v2 = xw2[(size_t)ra2 * 32 + fl];
            __half2 v3 = xw2[(size_t)ra3 * 32 + fl];
            __half2 v4 = xw2[(size_t)ra4 * 32 + fl];
            __half2 v5 = xw2[(size_t)ra5 * 32 + fl];
            __half2 v6 = xw2[(size_t)ra6 * 32 + fl];
            __half2 v7 = xw2[(size_t)ra7 * 32 + fl];
            float2 f;
            f = __half22float2(v0); ax = fmaf(wa0, f.x, ax); ay = fmaf(wa0, f.y, ay);
            f = __half22float2(v1); ax = fmaf(wa1, f.x, ax); ay = fmaf(wa1, f.y, ay);
            f = __half22float2(v2); ax = fmaf(wa2, f.x, ax); ay = fmaf(wa2, f.y, ay);
            f = __half22float2(v3); ax = fmaf(wa3, f.x, ax); ay = fmaf(wa3, f.y, ay);
            f = __half22float2(v4); ax = fmaf(wa4, f.x, ax); ay = fmaf(wa4, f.y, ay);
            f = __half22float2(v5); ax = fmaf(wa5, f.x, ax); ay = fmaf(wa5, f.y, ay);
            f = __half22float2(v6); ax = fmaf(wa6, f.x, ax); ay = fmaf(wa6, f.y, ay);
            f = __half22float2(v7); ax = fmaf(wa7, f.x, ax); ay = fmaf(wa7, f.y, ay);
        }
        for (; k + 1 < rem; k += 2) {
            int i = k + half_id;
            int ra = __shfl(r, i); float wa = __shfl(w, i);
            float2 f = __half22float2(xw2[(size_t)ra * 32 + fl]);
            ax = fmaf(wa, f.x, ax); ay = fmaf(wa, f.y, ay);
        }
        if (k < rem) {                 // single leftover edge: half 0 only
            int ra = __shfl(r, k); float wa = __shfl(w, k);
            if (half_id == 0) {
                float2 f = __half22float2(xw2[(size_t)ra * 32 + fl]);
                ax = fmaf(wa, f.x, ax); ay = fmaf(wa, f.y, ay);
            }
        }
    }
    // combine even/odd halves (partner lane has same fl)
    ax += __shfl(ax, lane ^ 32);
    ay += __shfl(ay, lane ^ 32);
    if (half_id == 0) {
        float d = dis[n];
        float2 xs = __half22float2(xw2[(size_t)n * 32 + fl]);
        float2 bb = reinterpret_cast<const float2*>(bias)[fl];
        float2 out;
        out.x = fmaxf(fmaf(d, fmaf(d, xs.x, ax), bb.x), 0.0f);
        out.y = fmaxf(fmaf(d, fmaf(d, xs.y, ay), bb.y), 0.0f);
        hout[(size_t)n * 32 + fl] = __float22half2_rn(out);
        if constexpr (WITH_LOGITS) {
            float2 awv = reinterpret_cast<const float2*>(aw)[fl];
            float lg = out.x * awv.x + out.y * awv.y;
            lg += __shfl(lg, lane ^ 1);
            lg += __shfl(lg, lane ^ 2);
            lg += __shfl(lg, lane ^ 4);
            lg += __shfl(lg, lane ^ 8);
            lg += __shfl(lg, lane ^ 16);
            if (lane == 0) logits[n] = lg + ab[0];
        }
    }
}

// Pool-only heads: wave per contiguous node chunk (batch sorted); lanes 0-31
// hold feature pairs, register accumulation, flush on graph transition.
__global__ __launch_bounds__(256) void pool_k(const __half2* __restrict__ h2,
                                              const int* __restrict__ batch,
                                              float* __restrict__ sums,
                                              float* __restrict__ counts,
                                              int N, int C) {
    int wave = blockIdx.x * 4 + (threadIdx.x >> 6);
    int lane = threadIdx.x & 63;
    int start = wave * C;
    if (start >= N) return;
    if (lane >= 32) return;            // half-wave idle (stream is tiny)
    int end = min(start + C, N);
    int fl = lane;
    int cur = batch[start];
    float accx = 0.f, accy = 0.f;
    int cntv = 0;
    for (int i = start; i < end; ++i) {
        float2 v = __half22float2(h2[(size_t)i * 32 + fl]);
        int g = batch[i];                     // wave-uniform
        if (g != cur) {
            atomicAdd(&sums[cur * 64 + 2 * fl], accx);
            atomicAdd(&sums[cur * 64 + 2 * fl + 1], accy);
            if (fl == 0) atomicAdd(&counts[cur], (float)cntv);
            accx = 0.f; accy = 0.f; cntv = 0; cur = g;
        }
        accx += v.x; accy += v.y; ++cntv;
    }
    atomicAdd(&sums[cur * 64 + 2 * fl], accx);
    atomicAdd(&sums[cur * 64 + 2 * fl + 1], accy);
    if (fl == 0) atomicAdd(&counts[cur], (float)cntv);
}

__global__ void value_k(const float* __restrict__ sums, const float* __restrict__ counts,
                        const float* __restrict__ cw, const float* __restrict__ cb,
                        float* __restrict__ val) {
    int g = blockIdx.x;
    int lane = threadIdx.x;  // block 64
    float cntv = fmaxf(counts[g], 1.0f);
    float p = (sums[g * 64 + lane] / cntv) * cw[lane];
    for (int off = 32; off; off >>= 1) p += __shfl_down(p, off);
    if (lane == 0) val[g] = p + cb[0];
}

extern "C" void kernel_launch(void* const* d_in, const int* in_sizes, int n_in,
                              void* d_out, int out_size, void* d_ws, size_t ws_size,
                              hipStream_t stream) {
    const float* x     = (const float*)d_in[0];
    const int*   ei    = (const int*)d_in[1];
    const float* ea    = (const float*)d_in[2];
    const int*   batch = (const int*)d_in[3];
    const float* W1    = (const float*)d_in[4];
    const float* b1    = (const float*)d_in[5];
    const float* W2    = (const float*)d_in[6];
    const float* b2    = (const float*)d_in[7];
    const float* aw    = (const float*)d_in[8];
    const float* ab    = (const float*)d_in[9];
    const float* cw    = (const float*)d_in[10];
    const float* cb    = (const float*)d_in[11];

    const int N = in_sizes[3];
    const int E = in_sizes[2];
    const int H = 64, G = 64;
    const int* row = ei;
    const int* col = ei + E;

    const int NB1  = (N + BW2 - 1) >> BSH2;                // coarse buckets (<=256)
    const int CAPB = (((E / NB1) * 5 / 4 + 256) + 1) & ~1; // ~1.25x mean, even

    // workspace layout (~53 MB). sums/counts/gCur colocated -> ONE memset.
    float*  sums   = (float*)d_ws;                          // G*H
    float*  counts = sums + G * H;                          // G
    int*    gCur   = (int*)(counts + G);                    // NB1MAX
    float*  dis    = (float*)(gCur + NB1MAX);               // N
    uint2*  recA   = (uint2*)(dis + N);                     // NB1*CAPB (8B rec)
    uint2*  rec    = recA + (size_t)NB1 * CAPB;             // NB1*CAPB
    int*    ptr    = (int*)(rec + (size_t)NB1 * CAPB);      // N
    int*    cnt    = ptr + N;                               // N
    __half* xwh    = (__half*)(cnt + N);                    // N*H fp16
    __half* hbuf   = xwh + (size_t)N * H;                   // N*H fp16

    float* logits = (float*)d_out;              // N
    float* value  = logits + N;                 // G

    // ---- one memset: sums + counts + gCur ----
    hipMemsetAsync(sums, 0, (size_t)(G * H + G + NB1MAX) * 4, stream);

    // ---- CSR build (shared by both layers; includes dis) ----
    passA_k<<<(E + CHUNK - 1) / CHUNK, 256, 0, stream>>>(col, row, ea, gCur, recA, E, CAPB, NB1);
    passB_k<<<NB1, 256, 0, stream>>>(gCur, recA, rec, ptr, cnt, dis, N, CAPB);

    // ---- layer 1 ----
    gemm_k<128, float><<<(N + 15) / 16, 256, 0, stream>>>(x, W1, xwh, N);
    agg_fin_k<false><<<(N + 3) / 4, 256, 0, stream>>>(ptr, cnt, rec, dis,
        (const __half2*)xwh, b1, (__half2*)hbuf, nullptr, nullptr, nullptr, N);

    // ---- layer 2 (logits fused into epilogue) ----
    gemm_k<64, __half><<<(N + 15) / 16, 256, 0, stream>>>(hbuf, W2, xwh, N);
    agg_fin_k<true><<<(N + 3) / 4, 256, 0, stream>>>(ptr, cnt, rec, dis,
        (const __half2*)xwh, b2, (__half2*)hbuf, aw, ab, logits, N);

    // ---- heads: pool + value ----
    const int WAVES = 4096;
    const int C = (N + WAVES - 1) / WAVES;
    pool_k<<<WAVES / 4, 256, 0, stream>>>((const __half2*)hbuf, batch, sums, counts, N, C);
    value_k<<<G, 64, 0, stream>>>(sums, counts, cw, cb, value);
}

// Round 14
// 256.027 us; speedup vs baseline: 1.0844x; 1.0844x over previous
//
#include <hip/hip_runtime.h>
#include <hip/hip_fp16.h>

// GNNPolicy forward: 2-layer GCN + actor head + mean-pool critic head.
// N=100K, E=1.6M, H=64, G=64. CSR build: 2-level counting sort; per-node
// segments PADDED to a multiple of 8 with (row=0,w=0) records so the
// aggregation inner loop is a single uniform 8-edge unrolled body with 4
// independent gathers in flight per lane (no serial tail). xw/h fp16.

#define TB 256
#define BSH2 9
#define BW2 512          // nodes per coarse bucket
#define CHUNK 4096       // edges per passA block
#define NB1MAX 256       // max coarse buckets (N <= 131072, row fits 17 bits)
#define PAD 8            // per-node segment padding multiple

// ---- pass A: LDS histogram + region reservation + dense 8B-record append ----
// recA = ( (colLocal<<17) | row , |ea| )
__global__ __launch_bounds__(256) void passA_k(const int* __restrict__ col,
                                               const int* __restrict__ row,
                                               const float* __restrict__ ea,
                                               int* __restrict__ gCur,
                                               uint2* __restrict__ recA,
                                               int E, int CAPB, int NB1) {
    __shared__ int hist[NB1MAX], base[NB1MAX], cur[NB1MAX];
    int t = threadIdx.x;
    int e0 = blockIdx.x * CHUNK;
    if (t < NB1MAX) { hist[t] = 0; cur[t] = 0; }
    __syncthreads();
    for (int i = t; i < CHUNK; i += 256) {
        int e = e0 + i;
        if (e < E) atomicAdd(&hist[col[e] >> BSH2], 1);
    }
    __syncthreads();
    if (t < NB1) base[t] = atomicAdd(&gCur[t], hist[t]);
    __syncthreads();
    for (int i = t; i < CHUNK; i += 256) {
        int e = e0 + i;
        if (e >= E) continue;
        int c = col[e];
        int b = c >> BSH2;
        int pos = base[b] + atomicAdd(&cur[b], 1);
        if (pos < CAPB)   // statistically impossible overflow; guard anyway
            recA[(size_t)b * CAPB + pos] =
                make_uint2(((unsigned)(c & (BW2 - 1)) << 17) | (unsigned)row[e],
                           __float_as_uint(fabsf(ea[e])));
    }
}

// ---- pass B: per-bucket binning -> PADDED CSR (row,|ea|) + ptr/cnt + dis ----
__global__ __launch_bounds__(256) void passB_k(const int* __restrict__ gCur,
                                               const uint2* __restrict__ recA,
                                               uint2* __restrict__ rec,
                                               int* __restrict__ ptr,
                                               int* __restrict__ cnt,
                                               float* __restrict__ dis,
                                               int N, int CAPB) {
    __shared__ int hist[BW2], excl[BW2], cur[BW2];
    __shared__ float sumL[BW2];
    __shared__ int part[256];
    int b = blockIdx.x, t = threadIdx.x;
    int nrec = min(gCur[b], CAPB);
    for (int i = t; i < BW2; i += 256) { hist[i] = 0; cur[i] = 0; sumL[i] = 0.f; }
    __syncthreads();
    const uint2* ra = recA + (size_t)b * CAPB;
    for (int i = t; i < nrec; i += 256) {
        uint2 r = ra[i];
        int lc = r.x >> 17;
        atomicAdd(&hist[lc], 1);
        atomicAdd(&sumL[lc], __uint_as_float(r.y));
    }
    __syncthreads();
    // block exclusive scan over 512 PADDED counters (2 per thread)
    int p0 = (hist[t * 2] + PAD - 1) & ~(PAD - 1);
    int p1 = (hist[t * 2 + 1] + PAD - 1) & ~(PAD - 1);
    int s = p0 + p1;
    part[t] = s;
    __syncthreads();
    for (int d = 1; d < 256; d <<= 1) {
        int v = (t >= d) ? part[t - d] : 0;
        __syncthreads();
        part[t] += v;
        __syncthreads();
    }
    int poff = t ? part[t - 1] : 0;
    excl[t * 2] = poff;
    excl[t * 2 + 1] = poff + p0;
    __syncthreads();
    for (int i = t; i < nrec; i += 256) {     // recA bucket is L2-hot (re-read)
        uint2 r = ra[i];
        int lc = r.x >> 17;
        int pos = atomicAdd(&cur[lc], 1);
        rec[(size_t)b * CAPB + excl[lc] + pos] = make_uint2(r.x & 0x1FFFFu, r.y);
    }
    __syncthreads();
    int c0 = b << BSH2;
    for (int i = t; i < BW2; i += 256) {
        int node = c0 + i;
        int hv = hist[i];
        int pc = (hv + PAD - 1) & ~(PAD - 1);
        // fill pad slots with (row=0, w=0): contributes exactly 0, L1-hot row
        for (int j = hv; j < pc; ++j)
            rec[(size_t)b * CAPB + excl[i] + j] = make_uint2(0u, 0u);
        if (node < N) {
            ptr[node] = b * CAPB + excl[i];
            cnt[node] = pc;                        // padded count (mult of 8)
            dis[node] = rsqrtf(sumL[i] + 1.0f);
        }
    }
}

// Y[N,64] = X[N,K] @ W[K,64], output fp16. 256 thr = 16 rows x 64 cols.
// T = float (layer 1) or __half (layer 2); LDS/accumulation stay f32.
template <int K, typename T>
__global__ __launch_bounds__(256) void gemm_k(const T* __restrict__ X,
                                              const float* __restrict__ W,
                                              __half* __restrict__ Y, int N) {
    __shared__ float xs[16 * K];
    const int tid = threadIdx.x;
    const int row0 = blockIdx.x * 16;
    float4* xs4 = reinterpret_cast<float4*>(xs);
    if constexpr (sizeof(T) == 4) {
        const float4* X4 = reinterpret_cast<const float4*>((const float*)X + (size_t)row0 * K);
        for (int idx = tid; idx < 16 * K / 4; idx += 256) {
            int r = row0 + (idx * 4) / K;
            xs4[idx] = (r < N) ? X4[idx] : float4{0.f, 0.f, 0.f, 0.f};
        }
    } else {
        const __half2* X2 = reinterpret_cast<const __half2*>((const __half*)X + (size_t)row0 * K);
        for (int idx = tid; idx < 16 * K / 4; idx += 256) {
            int r = row0 + (idx * 4) / K;
            if (r < N) {
                float2 fa = __half22float2(X2[2 * idx]);
                float2 fb = __half22float2(X2[2 * idx + 1]);
                xs4[idx] = float4{fa.x, fa.y, fb.x, fb.y};
            } else xs4[idx] = float4{0.f, 0.f, 0.f, 0.f};
        }
    }
    __syncthreads();
    const int c  = tid & 63;
    const int rg = tid >> 6;
    const float4* xp0 = reinterpret_cast<const float4*>(xs + (rg * 4 + 0) * K);
    const float4* xp1 = reinterpret_cast<const float4*>(xs + (rg * 4 + 1) * K);
    const float4* xp2 = reinterpret_cast<const float4*>(xs + (rg * 4 + 2) * K);
    const float4* xp3 = reinterpret_cast<const float4*>(xs + (rg * 4 + 3) * K);
    float a0 = 0.f, a1 = 0.f, a2 = 0.f, a3 = 0.f;
#pragma unroll 2
    for (int k4 = 0; k4 < K / 4; ++k4) {
        float4 x0 = xp0[k4], x1 = xp1[k4], x2 = xp2[k4], x3 = xp3[k4];
        const float* wp = W + k4 * 4 * 64 + c;
        float w0 = wp[0], w1 = wp[64], w2 = wp[128], w3 = wp[192];
        a0 = fmaf(x0.x, w0, a0); a0 = fmaf(x0.y, w1, a0);
        a0 = fmaf(x0.z, w2, a0); a0 = fmaf(x0.w, w3, a0);
        a1 = fmaf(x1.x, w0, a1); a1 = fmaf(x1.y, w1, a1);
        a1 = fmaf(x1.z, w2, a1); a1 = fmaf(x1.w, w3, a1);
        a2 = fmaf(x2.x, w0, a2); a2 = fmaf(x2.y, w1, a2);
        a2 = fmaf(x2.z, w2, a2); a2 = fmaf(x2.w, w3, a2);
        a3 = fmaf(x3.x, w0, a3); a3 = fmaf(x3.y, w1, a3);
        a3 = fmaf(x3.z, w2, a3); a3 = fmaf(x3.w, w3, a3);
    }
    int r = row0 + rg * 4;
    if (r < N)     Y[(size_t)r * 64 + c]       = __float2half(a0);
    if (r + 1 < N) Y[(size_t)(r + 1) * 64 + c] = __float2half(a1);
    if (r + 2 < N) Y[(size_t)(r + 2) * 64 + c] = __float2half(a2);
    if (r + 3 < N) Y[(size_t)(r + 3) * 64 + c] = __float2half(a3);
}

// CSR gather aggregation fused with self-loop + bias + ReLU (+ actor logits
// for layer 2). Wave per node; 2 edges per step: lanes 0-31 even edges,
// 32-63 odd edges; each lane loads one half2. Segments padded to mult of 8
// -> single uniform 8-edge unrolled body, 4 loads in flight per lane.
template <bool WITH_LOGITS>
__global__ __launch_bounds__(256) void agg_fin_k(const int* __restrict__ ptr,
                                                 const int* __restrict__ cnt,
                                                 const uint2* __restrict__ rec,
                                                 const float* __restrict__ dis,
                                                 const __half2* __restrict__ xw2,
                                                 const float* __restrict__ bias,
                                                 __half2* __restrict__ hout,
                                                 const float* __restrict__ aw,
                                                 const float* __restrict__ ab,
                                                 float* __restrict__ logits, int N) {
    int n = blockIdx.x * 4 + (threadIdx.x >> 6);
    if (n >= N) return;
    int lane = threadIdx.x & 63;
    int half_id = lane >> 5;          // 0: even edges, 1: odd edges
    int fl = lane & 31;               // feature pair (2fl, 2fl+1)
    int base = ptr[n], num = cnt[n];  // num % 8 == 0 (padded)
    float ax = 0.f, ay = 0.f;
    for (int k0 = 0; k0 < num; k0 += 64) {
        int rem = min(num - k0, 64);  // multiple of 8
        int r = 0; float w = 0.f;
        if (lane < rem) {
            uint2 rv = rec[(size_t)base + k0 + lane];   // coalesced 512B
            r = (int)rv.x;
            w = __uint_as_float(rv.y) * dis[r];         // 400KB table: L2-hot
        }
        for (int k = 0; k < rem; k += 8) {
            int i0 = k + half_id;
            int   ra0 = __shfl(r, i0),     ra1 = __shfl(r, i0 + 2);
            int   ra2 = __shfl(r, i0 + 4), ra3 = __shfl(r, i0 + 6);
            float wa0 = __shfl(w, i0),     wa1 = __shfl(w, i0 + 2);
            float wa2 = __shfl(w, i0 + 4), wa3 = __shfl(w, i0 + 6);
            __half2 v0 = xw2[(size_t)ra0 * 32 + fl];
            __half2 v1 = xw2[(size_t)ra1 * 32 + fl];
            __half2 v2 = xw2[(size_t)ra2 * 32 + fl];
            __half2 v3 = xw2[(size_t)ra3 * 32 + fl];
            float2 f;
            f = __half22float2(v0); ax = fmaf(wa0, f.x, ax); ay = fmaf(wa0, f.y, ay);
            f = __half22float2(v1); ax = fmaf(wa1, f.x, ax); ay = fmaf(wa1, f.y, ay);
            f = __half22float2(v2); ax = fmaf(wa2, f.x, ax); ay = fmaf(wa2, f.y, ay);
            f = __half22float2(v3); ax = fmaf(wa3, f.x, ax); ay = fmaf(wa3, f.y, ay);
        }
    }
    // combine even/odd halves (partner lane has same fl)
    ax += __shfl(ax, lane ^ 32);
    ay += __shfl(ay, lane ^ 32);
    if (half_id == 0) {
        float d = dis[n];
        float2 xs = __half22float2(xw2[(size_t)n * 32 + fl]);
        float2 bb = reinterpret_cast<const float2*>(bias)[fl];
        float2 out;
        out.x = fmaxf(fmaf(d, fmaf(d, xs.x, ax), bb.x), 0.0f);
        out.y = fmaxf(fmaf(d, fmaf(d, xs.y, ay), bb.y), 0.0f);
        hout[(size_t)n * 32 + fl] = __float22half2_rn(out);
        if constexpr (WITH_LOGITS) {
            float2 awv = reinterpret_cast<const float2*>(aw)[fl];
            float lg = out.x * awv.x + out.y * awv.y;
            lg += __shfl(lg, lane ^ 1);
            lg += __shfl(lg, lane ^ 2);
            lg += __shfl(lg, lane ^ 4);
            lg += __shfl(lg, lane ^ 8);
            lg += __shfl(lg, lane ^ 16);
            if (lane == 0) logits[n] = lg + ab[0];
        }
    }
}

// Pool-only heads: wave per contiguous node chunk (batch sorted); lanes 0-31
// hold feature pairs, register accumulation, flush on graph transition.
__global__ __launch_bounds__(256) void pool_k(const __half2* __restrict__ h2,
                                              const int* __restrict__ batch,
                                              float* __restrict__ sums,
                                              float* __restrict__ counts,
                                              int N, int C) {
    int wave = blockIdx.x * 4 + (threadIdx.x >> 6);
    int lane = threadIdx.x & 63;
    int start = wave * C;
    if (start >= N) return;
    if (lane >= 32) return;            // half-wave idle (stream is tiny)
    int end = min(start + C, N);
    int fl = lane;
    int cur = batch[start];
    float accx = 0.f, accy = 0.f;
    int cntv = 0;
    for (int i = start; i < end; ++i) {
        float2 v = __half22float2(h2[(size_t)i * 32 + fl]);
        int g = batch[i];                     // wave-uniform
        if (g != cur) {
            atomicAdd(&sums[cur * 64 + 2 * fl], accx);
            atomicAdd(&sums[cur * 64 + 2 * fl + 1], accy);
            if (fl == 0) atomicAdd(&counts[cur], (float)cntv);
            accx = 0.f; accy = 0.f; cntv = 0; cur = g;
        }
        accx += v.x; accy += v.y; ++cntv;
    }
    atomicAdd(&sums[cur * 64 + 2 * fl], accx);
    atomicAdd(&sums[cur * 64 + 2 * fl + 1], accy);
    if (fl == 0) atomicAdd(&counts[cur], (float)cntv);
}

__global__ void value_k(const float* __restrict__ sums, const float* __restrict__ counts,
                        const float* __restrict__ cw, const float* __restrict__ cb,
                        float* __restrict__ val) {
    int g = blockIdx.x;
    int lane = threadIdx.x;  // block 64
    float cntv = fmaxf(counts[g], 1.0f);
    float p = (sums[g * 64 + lane] / cntv) * cw[lane];
    for (int off = 32; off; off >>= 1) p += __shfl_down(p, off);
    if (lane == 0) val[g] = p + cb[0];
}

extern "C" void kernel_launch(void* const* d_in, const int* in_sizes, int n_in,
                              void* d_out, int out_size, void* d_ws, size_t ws_size,
                              hipStream_t stream) {
    const float* x     = (const float*)d_in[0];
    const int*   ei    = (const int*)d_in[1];
    const float* ea    = (const float*)d_in[2];
    const int*   batch = (const int*)d_in[3];
    const float* W1    = (const float*)d_in[4];
    const float* b1    = (const float*)d_in[5];
    const float* W2    = (const float*)d_in[6];
    const float* b2    = (const float*)d_in[7];
    const float* aw    = (const float*)d_in[8];
    const float* ab    = (const float*)d_in[9];
    const float* cw    = (const float*)d_in[10];
    const float* cb    = (const float*)d_in[11];

    const int N = in_sizes[3];
    const int E = in_sizes[2];
    const int H = 64, G = 64;
    const int* row = ei;
    const int* col = ei + E;

    const int NB1  = (N + BW2 - 1) >> BSH2;                // coarse buckets (<=256)
    const int CAPB = (((E / NB1) * 3 / 2 + 512) + 1) & ~1; // 1.5x mean (padding slack)

    // workspace layout (~60 MB). sums/counts/gCur colocated -> ONE memset.
    float*  sums   = (float*)d_ws;                          // G*H
    float*  counts = sums + G * H;                          // G
    int*    gCur   = (int*)(counts + G);                    // NB1MAX
    float*  dis    = (float*)(gCur + NB1MAX);               // N
    uint2*  recA   = (uint2*)(dis + N);                     // NB1*CAPB (8B rec)
    uint2*  rec    = recA + (size_t)NB1 * CAPB;             // NB1*CAPB
    int*    ptr    = (int*)(rec + (size_t)NB1 * CAPB);      // N
    int*    cnt    = ptr + N;                               // N
    __half* xwh    = (__half*)(cnt + N);                    // N*H fp16
    __half* hbuf   = xwh + (size_t)N * H;                   // N*H fp16

    float* logits = (float*)d_out;              // N
    float* value  = logits + N;                 // G

    // ---- one memset: sums + counts + gCur ----
    hipMemsetAsync(sums, 0, (size_t)(G * H + G + NB1MAX) * 4, stream);

    // ---- CSR build (shared by both layers; includes dis + padding) ----
    passA_k<<<(E + CHUNK - 1) / CHUNK, 256, 0, stream>>>(col, row, ea, gCur, recA, E, CAPB, NB1);
    passB_k<<<NB1, 256, 0, stream>>>(gCur, recA, rec, ptr, cnt, dis, N, CAPB);

    // ---- layer 1 ----
    gemm_k<128, float><<<(N + 15) / 16, 256, 0, stream>>>(x, W1, xwh, N);
    agg_fin_k<false><<<(N + 3) / 4, 256, 0, stream>>>(ptr, cnt, rec, dis,
        (const __half2*)xwh, b1, (__half2*)hbuf, nullptr, nullptr, nullptr, N);

    // ---- layer 2 (logits fused into epilogue) ----
    gemm_k<64, __half><<<(N + 15) / 16, 256, 0, stream>>>(hbuf, W2, xwh, N);
    agg_fin_k<true><<<(N + 3) / 4, 256, 0, stream>>>(ptr, cnt, rec, dis,
        (const __half2*)xwh, b2, (__half2*)hbuf, aw, ab, logits, N);

    // ---- heads: pool + value ----
    const int WAVES = 4096;
    const int C = (N + WAVES - 1) / WAVES;
    pool_k<<<WAVES / 4, 256, 0, stream>>>((const __half2*)hbuf, batch, sums, counts, N, C);
    value_k<<<G, 64, 0, stream>>>(sums, counts, cw, cb, value);
}

// Round 15
// 251.359 us; speedup vs baseline: 1.1045x; 1.0186x over previous
//
#include <hip/hip_runtime.h>
#include <hip/hip_fp16.h>

// GNNPolicy forward: 2-layer GCN + actor head + mean-pool critic head.
// N=100K, E=1.6M, H=64, G=64. CSR build: 2-level counting sort; per-node
// segments padded to a multiple of 8 (uniform 8-edge unrolled gather body).
// xw/h fp16 (f32 accumulation). gemm: 64x64 tile, 4 rows x 4 cols per thread
// (each LDS b128 read feeds 16 FMAs -> VALU-bound, not LDS-port-bound).

#define TB 256
#define BSH2 9
#define BW2 512          // nodes per coarse bucket
#define CHUNK 4096       // edges per passA block
#define NB1MAX 256       // max coarse buckets (N <= 131072, row fits 17 bits)
#define PAD 8            // per-node segment padding multiple

// ---- pass A: LDS histogram + region reservation + dense 8B-record append ----
// recA = ( (colLocal<<17) | row , |ea| )
__global__ __launch_bounds__(256) void passA_k(const int* __restrict__ col,
                                               const int* __restrict__ row,
                                               const float* __restrict__ ea,
                                               int* __restrict__ gCur,
                                               uint2* __restrict__ recA,
                                               int E, int CAPB, int NB1) {
    __shared__ int hist[NB1MAX], base[NB1MAX], cur[NB1MAX];
    int t = threadIdx.x;
    int e0 = blockIdx.x * CHUNK;
    if (t < NB1MAX) { hist[t] = 0; cur[t] = 0; }
    __syncthreads();
    for (int i = t; i < CHUNK; i += 256) {
        int e = e0 + i;
        if (e < E) atomicAdd(&hist[col[e] >> BSH2], 1);
    }
    __syncthreads();
    if (t < NB1) base[t] = atomicAdd(&gCur[t], hist[t]);
    __syncthreads();
    for (int i = t; i < CHUNK; i += 256) {
        int e = e0 + i;
        if (e >= E) continue;
        int c = col[e];
        int b = c >> BSH2;
        int pos = base[b] + atomicAdd(&cur[b], 1);
        if (pos < CAPB)   // statistically impossible overflow; guard anyway
            recA[(size_t)b * CAPB + pos] =
                make_uint2(((unsigned)(c & (BW2 - 1)) << 17) | (unsigned)row[e],
                           __float_as_uint(fabsf(ea[e])));
    }
}

// ---- pass B: per-bucket binning -> PADDED CSR (row,|ea|) + ptr/cnt + dis ----
__global__ __launch_bounds__(256) void passB_k(const int* __restrict__ gCur,
                                               const uint2* __restrict__ recA,
                                               uint2* __restrict__ rec,
                                               int* __restrict__ ptr,
                                               int* __restrict__ cnt,
                                               float* __restrict__ dis,
                                               int N, int CAPB) {
    __shared__ int hist[BW2], excl[BW2], cur[BW2];
    __shared__ float sumL[BW2];
    __shared__ int part[256];
    int b = blockIdx.x, t = threadIdx.x;
    int nrec = min(gCur[b], CAPB);
    for (int i = t; i < BW2; i += 256) { hist[i] = 0; cur[i] = 0; sumL[i] = 0.f; }
    __syncthreads();
    const uint2* ra = recA + (size_t)b * CAPB;
    for (int i = t; i < nrec; i += 256) {
        uint2 r = ra[i];
        int lc = r.x >> 17;
        atomicAdd(&hist[lc], 1);
        atomicAdd(&sumL[lc], __uint_as_float(r.y));
    }
    __syncthreads();
    // block exclusive scan over 512 PADDED counters (2 per thread)
    int p0 = (hist[t * 2] + PAD - 1) & ~(PAD - 1);
    int p1 = (hist[t * 2 + 1] + PAD - 1) & ~(PAD - 1);
    int s = p0 + p1;
    part[t] = s;
    __syncthreads();
    for (int d = 1; d < 256; d <<= 1) {
        int v = (t >= d) ? part[t - d] : 0;
        __syncthreads();
        part[t] += v;
        __syncthreads();
    }
    int poff = t ? part[t - 1] : 0;
    excl[t * 2] = poff;
    excl[t * 2 + 1] = poff + p0;
    __syncthreads();
    for (int i = t; i < nrec; i += 256) {     // recA bucket is L2-hot (re-read)
        uint2 r = ra[i];
        int lc = r.x >> 17;
        int pos = atomicAdd(&cur[lc], 1);
        rec[(size_t)b * CAPB + excl[lc] + pos] = make_uint2(r.x & 0x1FFFFu, r.y);
    }
    __syncthreads();
    int c0 = b << BSH2;
    for (int i = t; i < BW2; i += 256) {
        int node = c0 + i;
        int hv = hist[i];
        int pc = (hv + PAD - 1) & ~(PAD - 1);
        // fill pad slots with (row=0, w=0): contributes exactly 0, L1-hot row
        for (int j = hv; j < pc; ++j)
            rec[(size_t)b * CAPB + excl[i] + j] = make_uint2(0u, 0u);
        if (node < N) {
            ptr[node] = b * CAPB + excl[i];
            cnt[node] = pc;                        // padded count (mult of 8)
            dis[node] = rsqrtf(sumL[i] + 1.0f);
        }
    }
}

// Y[N,64] = X[N,K] @ W[K,64], output fp16. 64x64 tile, 256 thr = 16 rg x 16 cg,
// 4 rows x 4 cols per thread: each LDS b128 read feeds 16 FMAs.
// T = float (layer 1) or __half (layer 2); LDS/accumulation stay f32.
#define FMA_ROW(ar, xv)                                                        \
    ar.x = fmaf(xv.x, w0.x, ar.x); ar.y = fmaf(xv.x, w0.y, ar.y);              \
    ar.z = fmaf(xv.x, w0.z, ar.z); ar.w = fmaf(xv.x, w0.w, ar.w);              \
    ar.x = fmaf(xv.y, w1.x, ar.x); ar.y = fmaf(xv.y, w1.y, ar.y);              \
    ar.z = fmaf(xv.y, w1.z, ar.z); ar.w = fmaf(xv.y, w1.w, ar.w);              \
    ar.x = fmaf(xv.z, w2.x, ar.x); ar.y = fmaf(xv.z, w2.y, ar.y);              \
    ar.z = fmaf(xv.z, w2.z, ar.z); ar.w = fmaf(xv.z, w2.w, ar.w);              \
    ar.x = fmaf(xv.w, w3.x, ar.x); ar.y = fmaf(xv.w, w3.y, ar.y);              \
    ar.z = fmaf(xv.w, w3.z, ar.z); ar.w = fmaf(xv.w, w3.w, ar.w);

template <int K, typename T>
__global__ __launch_bounds__(256) void gemm_k(const T* __restrict__ X,
                                              const float* __restrict__ W,
                                              __half* __restrict__ Y, int N) {
    __shared__ float xs[64 * K];
    const int tid = threadIdx.x;
    const int row0 = blockIdx.x * 64;
    float4* xs4 = reinterpret_cast<float4*>(xs);
    if constexpr (sizeof(T) == 4) {
        const float4* X4 = reinterpret_cast<const float4*>((const float*)X + (size_t)row0 * K);
        for (int idx = tid; idx < 64 * K / 4; idx += 256) {
            int r = row0 + (idx * 4) / K;
            xs4[idx] = (r < N) ? X4[idx] : float4{0.f, 0.f, 0.f, 0.f};
        }
    } else {
        const __half2* X2 = reinterpret_cast<const __half2*>((const __half*)X + (size_t)row0 * K);
        for (int idx = tid; idx < 64 * K / 4; idx += 256) {
            int r = row0 + (idx * 4) / K;
            if (r < N) {
                float2 fa = __half22float2(X2[2 * idx]);
                float2 fb = __half22float2(X2[2 * idx + 1]);
                xs4[idx] = float4{fa.x, fa.y, fb.x, fb.y};
            } else xs4[idx] = float4{0.f, 0.f, 0.f, 0.f};
        }
    }
    __syncthreads();
    const int cg = tid & 15;          // cols 4*cg .. 4*cg+3
    const int rg = tid >> 4;          // rows 4*rg .. 4*rg+3
    const float4* W4 = reinterpret_cast<const float4*>(W);   // W4[k*16 + cg]
    const float4* xr0 = reinterpret_cast<const float4*>(xs + (rg * 4 + 0) * K);
    const float4* xr1 = reinterpret_cast<const float4*>(xs + (rg * 4 + 1) * K);
    const float4* xr2 = reinterpret_cast<const float4*>(xs + (rg * 4 + 2) * K);
    const float4* xr3 = reinterpret_cast<const float4*>(xs + (rg * 4 + 3) * K);
    float4 a0 = {0.f, 0.f, 0.f, 0.f}, a1 = a0, a2 = a0, a3 = a0;
#pragma unroll 2
    for (int k4 = 0; k4 < K / 4; ++k4) {
        float4 x0 = xr0[k4], x1 = xr1[k4], x2 = xr2[k4], x3 = xr3[k4];
        float4 w0 = W4[(k4 * 4 + 0) * 16 + cg];
        float4 w1 = W4[(k4 * 4 + 1) * 16 + cg];
        float4 w2 = W4[(k4 * 4 + 2) * 16 + cg];
        float4 w3 = W4[(k4 * 4 + 3) * 16 + cg];
        FMA_ROW(a0, x0)
        FMA_ROW(a1, x1)
        FMA_ROW(a2, x2)
        FMA_ROW(a3, x3)
    }
    int r = row0 + rg * 4;
    __half2* yp0 = reinterpret_cast<__half2*>(Y + (size_t)r * 64 + cg * 4);
    if (r < N) {
        yp0[0] = __float22half2_rn(make_float2(a0.x, a0.y));
        yp0[1] = __float22half2_rn(make_float2(a0.z, a0.w));
    }
    if (r + 1 < N) {
        __half2* yp = yp0 + 32;
        yp[0] = __float22half2_rn(make_float2(a1.x, a1.y));
        yp[1] = __float22half2_rn(make_float2(a1.z, a1.w));
    }
    if (r + 2 < N) {
        __half2* yp = yp0 + 64;
        yp[0] = __float22half2_rn(make_float2(a2.x, a2.y));
        yp[1] = __float22half2_rn(make_float2(a2.z, a2.w));
    }
    if (r + 3 < N) {
        __half2* yp = yp0 + 96;
        yp[0] = __float22half2_rn(make_float2(a3.x, a3.y));
        yp[1] = __float22half2_rn(make_float2(a3.z, a3.w));
    }
}

// CSR gather aggregation fused with self-loop + bias + ReLU (+ actor logits
// for layer 2). Wave per node; 2 edges per step: lanes 0-31 even edges,
// 32-63 odd edges; each lane loads one half2. Segments padded to mult of 8
// -> single uniform 8-edge unrolled body, 4 loads in flight per lane.
template <bool WITH_LOGITS>
__global__ __launch_bounds__(256) void agg_fin_k(const int* __restrict__ ptr,
                                                 const int* __restrict__ cnt,
                                                 const uint2* __restrict__ rec,
                                                 const float* __restrict__ dis,
                                                 const __half2* __restrict__ xw2,
                                                 const float* __restrict__ bias,
                                                 __half2* __restrict__ hout,
                                                 const float* __restrict__ aw,
                                                 const float* __restrict__ ab,
                                                 float* __restrict__ logits, int N) {
    int n = blockIdx.x * 4 + (threadIdx.x >> 6);
    if (n >= N) return;
    int lane = threadIdx.x & 63;
    int half_id = lane >> 5;          // 0: even edges, 1: odd edges
    int fl = lane & 31;               // feature pair (2fl, 2fl+1)
    int base = ptr[n], num = cnt[n];  // num % 8 == 0 (padded)
    float ax = 0.f, ay = 0.f;
    for (int k0 = 0; k0 < num; k0 += 64) {
        int rem = min(num - k0, 64);  // multiple of 8
        int r = 0; float w = 0.f;
        if (lane < rem) {
            uint2 rv = rec[(size_t)base + k0 + lane];   // coalesced 512B
            r = (int)rv.x;
            w = __uint_as_float(rv.y) * dis[r];         // 400KB table: L2-hot
        }
        for (int k = 0; k < rem; k += 8) {
            int i0 = k + half_id;
            int   ra0 = __shfl(r, i0),     ra1 = __shfl(r, i0 + 2);
            int   ra2 = __shfl(r, i0 + 4), ra3 = __shfl(r, i0 + 6);
            float wa0 = __shfl(w, i0),     wa1 = __shfl(w, i0 + 2);
            float wa2 = __shfl(w, i0 + 4), wa3 = __shfl(w, i0 + 6);
            __half2 v0 = xw2[(size_t)ra0 * 32 + fl];
            __half2 v1 = xw2[(size_t)ra1 * 32 + fl];
            __half2 v2 = xw2[(size_t)ra2 * 32 + fl];
            __half2 v3 = xw2[(size_t)ra3 * 32 + fl];
            float2 f;
            f = __half22float2(v0); ax = fmaf(wa0, f.x, ax); ay = fmaf(wa0, f.y, ay);
            f = __half22float2(v1); ax = fmaf(wa1, f.x, ax); ay = fmaf(wa1, f.y, ay);
            f = __half22float2(v2); ax = fmaf(wa2, f.x, ax); ay = fmaf(wa2, f.y, ay);
            f = __half22float2(v3); ax = fmaf(wa3, f.x, ax); ay = fmaf(wa3, f.y, ay);
        }
    }
    // combine even/odd halves (partner lane has same fl)
    ax += __shfl(ax, lane ^ 32);
    ay += __shfl(ay, lane ^ 32);
    if (half_id == 0) {
        float d = dis[n];
        float2 xs = __half22float2(xw2[(size_t)n * 32 + fl]);
        float2 bb = reinterpret_cast<const float2*>(bias)[fl];
        float2 out;
        out.x = fmaxf(fmaf(d, fmaf(d, xs.x, ax), bb.x), 0.0f);
        out.y = fmaxf(fmaf(d, fmaf(d, xs.y, ay), bb.y), 0.0f);
        hout[(size_t)n * 32 + fl] = __float22half2_rn(out);
        if constexpr (WITH_LOGITS) {
            float2 awv = reinterpret_cast<const float2*>(aw)[fl];
            float lg = out.x * awv.x + out.y * awv.y;
            lg += __shfl(lg, lane ^ 1);
            lg += __shfl(lg, lane ^ 2);
            lg += __shfl(lg, lane ^ 4);
            lg += __shfl(lg, lane ^ 8);
            lg += __shfl(lg, lane ^ 16);
            if (lane == 0) logits[n] = lg + ab[0];
        }
    }
}

// Pool-only heads: wave per contiguous node chunk (batch sorted); lanes 0-31
// hold feature pairs, register accumulation, flush on graph transition.
__global__ __launch_bounds__(256) void pool_k(const __half2* __restrict__ h2,
                                              const int* __restrict__ batch,
                                              float* __restrict__ sums,
                                              float* __restrict__ counts,
                                              int N, int C) {
    int wave = blockIdx.x * 4 + (threadIdx.x >> 6);
    int lane = threadIdx.x & 63;
    int start = wave * C;
    if (start >= N) return;
    if (lane >= 32) return;            // half-wave idle (stream is tiny)
    int end = min(start + C, N);
    int fl = lane;
    int cur = batch[start];
    float accx = 0.f, accy = 0.f;
    int cntv = 0;
    for (int i = start; i < end; ++i) {
        float2 v = __half22float2(h2[(size_t)i * 32 + fl]);
        int g = batch[i];                     // wave-uniform
        if (g != cur) {
            atomicAdd(&sums[cur * 64 + 2 * fl], accx);
            atomicAdd(&sums[cur * 64 + 2 * fl + 1], accy);
            if (fl == 0) atomicAdd(&counts[cur], (float)cntv);
            accx = 0.f; accy = 0.f; cntv = 0; cur = g;
        }
        accx += v.x; accy += v.y; ++cntv;
    }
    atomicAdd(&sums[cur * 64 + 2 * fl], accx);
    atomicAdd(&sums[cur * 64 + 2 * fl + 1], accy);
    if (fl == 0) atomicAdd(&counts[cur], (float)cntv);
}

__global__ void value_k(const float* __restrict__ sums, const float* __restrict__ counts,
                        const float* __restrict__ cw, const float* __restrict__ cb,
                        float* __restrict__ val) {
    int g = blockIdx.x;
    int lane = threadIdx.x;  // block 64
    float cntv = fmaxf(counts[g], 1.0f);
    float p = (sums[g * 64 + lane] / cntv) * cw[lane];
    for (int off = 32; off; off >>= 1) p += __shfl_down(p, off);
    if (lane == 0) val[g] = p + cb[0];
}

extern "C" void kernel_launch(void* const* d_in, const int* in_sizes, int n_in,
                              void* d_out, int out_size, void* d_ws, size_t ws_size,
                              hipStream_t stream) {
    const float* x     = (const float*)d_in[0];
    const int*   ei    = (const int*)d_in[1];
    const float* ea    = (const float*)d_in[2];
    const int*   batch = (const int*)d_in[3];
    const float* W1    = (const float*)d_in[4];
    const float* b1    = (const float*)d_in[5];
    const float* W2    = (const float*)d_in[6];
    const float* b2    = (const float*)d_in[7];
    const float* aw    = (const float*)d_in[8];
    const float* ab    = (const float*)d_in[9];
    const float* cw    = (const float*)d_in[10];
    const float* cb    = (const float*)d_in[11];

    const int N = in_sizes[3];
    const int E = in_sizes[2];
    const int H = 64, G = 64;
    const int* row = ei;
    const int* col = ei + E;

    const int NB1  = (N + BW2 - 1) >> BSH2;                // coarse buckets (<=256)
    const int CAPB = (((E / NB1) * 3 / 2 + 512) + 1) & ~1; // 1.5x mean (padding slack)

    // workspace layout (~60 MB). sums/counts/gCur colocated -> ONE memset.
    float*  sums   = (float*)d_ws;                          // G*H
    float*  counts = sums + G * H;                          // G
    int*    gCur   = (int*)(counts + G);                    // NB1MAX
    float*  dis    = (float*)(gCur + NB1MAX);               // N
    uint2*  recA   = (uint2*)(dis + N);                     // NB1*CAPB (8B rec)
    uint2*  rec    = recA + (size_t)NB1 * CAPB;             // NB1*CAPB
    int*    ptr    = (int*)(rec + (size_t)NB1 * CAPB);      // N
    int*    cnt    = ptr + N;                               // N
    __half* xwh    = (__half*)(cnt + N);                    // N*H fp16
    __half* hbuf   = xwh + (size_t)N * H;                   // N*H fp16

    float* logits = (float*)d_out;              // N
    float* value  = logits + N;                 // G

    // ---- one memset: sums + counts + gCur ----
    hipMemsetAsync(sums, 0, (size_t)(G * H + G + NB1MAX) * 4, stream);

    // ---- CSR build (shared by both layers; includes dis + padding) ----
    passA_k<<<(E + CHUNK - 1) / CHUNK, 256, 0, stream>>>(col, row, ea, gCur, recA, E, CAPB, NB1);
    passB_k<<<NB1, 256, 0, stream>>>(gCur, recA, rec, ptr, cnt, dis, N, CAPB);

    // ---- layer 1 ----
    gemm_k<128, float><<<(N + 63) / 64, 256, 0, stream>>>(x, W1, xwh, N);
    agg_fin_k<false><<<(N + 3) / 4, 256, 0, stream>>>(ptr, cnt, rec, dis,
        (const __half2*)xwh, b1, (__half2*)hbuf, nullptr, nullptr, nullptr, N);

    // ---- layer 2 (logits fused into epilogue) ----
    gemm_k<64, __half><<<(N + 63) / 64, 256, 0, stream>>>(hbuf, W2, xwh, N);
    agg_fin_k<true><<<(N + 3) / 4, 256, 0, stream>>>(ptr, cnt, rec, dis,
        (const __half2*)xwh, b2, (__half2*)hbuf, aw, ab, logits, N);

    // ---- heads: pool + value ----
    const int WAVES = 4096;
    const int C = (N + WAVES - 1) / WAVES;
    pool_k<<<WAVES / 4, 256, 0, stream>>>((const __half2*)hbuf, batch, sums, counts, N, C);
    value_k<<<G, 64, 0, stream>>>(sums, counts, cw, cb, value);
}